// Round 1
// baseline (1088.762 us; speedup 1.0000x reference)
//
#include <hip/hip_runtime.h>

#define BB  1024
#define TT  128
#define HH1 512
#define HH2 256
#define CC  18

// Transpose W2 (256 x 512) -> W2T (512 x 256). Row 512 of W2T (dummy/zero) is
// memset separately in kernel_launch.
__global__ __launch_bounds__(256) void transpose_w2(const float* __restrict__ in,
                                                    float* __restrict__ out)
{
  __shared__ float tile[32][33];
  int bx = blockIdx.x * 32;            // h1 (input col)
  int by = blockIdx.y * 32;            // h2 (input row)
  int tx = threadIdx.x & 31;
  int ty = threadIdx.x >> 5;           // 0..7
#pragma unroll
  for (int j = 0; j < 32; j += 8)
    tile[ty + j][tx] = in[(by + ty + j) * HH1 + bx + tx];
  __syncthreads();
#pragma unroll
  for (int j = 0; j < 32; j += 8)
    out[(bx + ty + j) * HH2 + by + tx] = tile[tx][ty + j];
}

// One block per batch row. 256 threads = 4 waves.
//   layer1: thread owns h1 = tid and tid+256 (v1 in regs)
//   layer2: thread owns h2 = tid (v2 in reg); active-h1 list from ballots
//   layer3: lanes 0..17 of every wave redundantly own c (v3/acc in regs);
//           wave 0 writes the output.
__global__ __launch_bounds__(256) void snn_main(const float* __restrict__ x,
    const float* __restrict__ W1, const float* __restrict__ b1,
    const float* __restrict__ W2T, const float* __restrict__ b2,
    const float* __restrict__ W3, const float* __restrict__ b3,
    float* __restrict__ out)
{
  __shared__ float xrow[TT];
  __shared__ float w3t[(HH2 + 1) * CC];          // +1 dummy zero row
  __shared__ unsigned long long m1s[8];
  __shared__ unsigned long long m2s[4];
  __shared__ unsigned short list1[4][520];       // per-wave copy, pad slack
  __shared__ unsigned short list2[4][264];

  const int b    = blockIdx.x;
  const int tid  = threadIdx.x;
  const int wv   = tid >> 6;
  const int lane = tid & 63;

  for (int i = tid; i < TT; i += 256) xrow[i] = x[b * TT + i];
  for (int i = tid; i < HH2 * CC; i += 256) {
    int c = i / HH2, h2 = i - c * HH2;
    w3t[h2 * CC + c] = W3[i];                    // w3t[h2][c] = W3[c][h2]
  }
  if (tid < CC) w3t[HH2 * CC + tid] = 0.0f;      // dummy row for padding

  const float w1a = W1[tid], w1b = W1[tid + 256];
  const float b1a = b1[tid], b1b = b1[tid + 256];
  const float b2r = b2[tid];
  const float b3r = (lane < CC) ? b3[lane] : 0.0f;

  float v1a = 0.0f, v1b = 0.0f, v2 = 0.0f, v3 = 0.0f, acc = 0.0f;

  __syncthreads();

  const float* w2col = W2T + tid;                // column h2=tid; rows stride HH2

  for (int t = 0; t < TT; ++t) {
    float xt = xrow[t];

    // ---- layer 1 (bit-exact vs numpy: mul-rn, add-rn, add-rn) ----
    float iA = __fadd_rn(__fmul_rn(xt, w1a), b1a);
    v1a = __fadd_rn(v1a, iA);
    bool sA = (v1a >= 1.0f);
    v1a = sA ? (v1a - 1.0f) : v1a;
    float iB = __fadd_rn(__fmul_rn(xt, w1b), b1b);
    v1b = __fadd_rn(v1b, iB);
    bool sB = (v1b >= 1.0f);
    v1b = sB ? (v1b - 1.0f) : v1b;
    unsigned long long mA = __ballot(sA);
    unsigned long long mB = __ballot(sB);
    if (lane == 0) { m1s[wv] = mA; m1s[4 + wv] = mB; }
    __syncthreads();

    // ---- build per-wave active-h1 list (identical across waves) ----
    int cj = (lane < 8) ? (int)__popcll(m1s[lane]) : 0;
    int inc = cj;
#pragma unroll
    for (int d = 1; d < 8; d <<= 1) {
      int up = __shfl_up(inc, d, 8);
      if ((lane & 7) >= d) inc += up;
    }
    int cnt1 = (int)(__popcll(m1s[0]) + __popcll(m1s[1]) + __popcll(m1s[2]) + __popcll(m1s[3])
                   + __popcll(m1s[4]) + __popcll(m1s[5]) + __popcll(m1s[6]) + __popcll(m1s[7]));
    if (lane < 8) {
      unsigned long long m = m1s[lane];
      int o = inc - cj;
      int base = lane * 64;
      while (m) {
        int bp = __builtin_ctzll(m);
        m &= m - 1;
        list1[wv][o++] = (unsigned short)(base + bp);
      }
    }
    int rcnt1 = (cnt1 + 7) & ~7;                  // pad with dummy row HH1 (zeros)
    if (lane < rcnt1 - cnt1) list1[wv][cnt1 + lane] = (unsigned short)HH1;

    // ---- layer 2: masked column-sum of W2T, 8 loads in flight ----
    float d2 = 0.0f;
    {
      const unsigned short* lp = list1[wv];
      for (int i0 = 0; i0 < cnt1; i0 += 8) {
        int   h[8];
        float f[8];
#pragma unroll
        for (int u = 0; u < 8; ++u) h[u] = lp[i0 + u];
#pragma unroll
        for (int u = 0; u < 8; ++u) f[u] = w2col[h[u] * HH2];
#pragma unroll
        for (int u = 0; u < 8; ++u) d2 = __fadd_rn(d2, f[u]);
      }
    }
    float i2 = __fadd_rn(d2, b2r);
    v2 = __fadd_rn(v2, i2);
    bool s2 = (v2 >= 1.0f);
    v2 = s2 ? (v2 - 1.0f) : v2;
    unsigned long long mW = __ballot(s2);
    if (lane == 0) m2s[wv] = mW;
    __syncthreads();

    // ---- layer 3 (redundant in every wave; tiny) ----
    int cj2 = (lane < 4) ? (int)__popcll(m2s[lane]) : 0;
    int inc2 = cj2;
#pragma unroll
    for (int d = 1; d < 4; d <<= 1) {
      int up = __shfl_up(inc2, d, 4);
      if ((lane & 3) >= d) inc2 += up;
    }
    int cnt2 = (int)(__popcll(m2s[0]) + __popcll(m2s[1]) + __popcll(m2s[2]) + __popcll(m2s[3]));
    if (lane < 4) {
      unsigned long long m = m2s[lane];
      int o = inc2 - cj2;
      int base = lane * 64;
      while (m) {
        int bp = __builtin_ctzll(m);
        m &= m - 1;
        list2[wv][o++] = (unsigned short)(base + bp);
      }
    }
    int rcnt2 = (cnt2 + 7) & ~7;                  // pad with dummy row HH2 (zeros)
    if (lane < rcnt2 - cnt2) list2[wv][cnt2 + lane] = (unsigned short)HH2;

    int c = (lane < CC) ? lane : 0;
    float d3 = 0.0f;
    {
      const unsigned short* lq = list2[wv];
      for (int i0 = 0; i0 < cnt2; i0 += 8) {
        int   h[8];
        float f[8];
#pragma unroll
        for (int u = 0; u < 8; ++u) h[u] = lq[i0 + u];
#pragma unroll
        for (int u = 0; u < 8; ++u) f[u] = w3t[h[u] * CC + c];
#pragma unroll
        for (int u = 0; u < 8; ++u) d3 = __fadd_rn(d3, f[u]);
      }
    }
    float i3 = __fadd_rn(d3, b3r);
    v3 = __fadd_rn(v3, i3);
    bool s3 = (v3 >= 1.0f);
    v3 = s3 ? (v3 - 1.0f) : v3;
    acc = __fadd_rn(acc, s3 ? 1.0f : 0.0f);
  }

  if (wv == 0 && lane < CC) out[b * CC + lane] = acc * (1.0f / TT);
}

extern "C" void kernel_launch(void* const* d_in, const int* in_sizes, int n_in,
                              void* d_out, int out_size, void* d_ws, size_t ws_size,
                              hipStream_t stream)
{
  (void)in_sizes; (void)n_in; (void)out_size; (void)ws_size;
  const float* x  = (const float*)d_in[0];
  const float* W1 = (const float*)d_in[1];
  const float* b1 = (const float*)d_in[2];
  const float* W2 = (const float*)d_in[3];
  const float* b2 = (const float*)d_in[4];
  const float* W3 = (const float*)d_in[5];
  const float* b3 = (const float*)d_in[6];
  // d_in[7] = repeat (==1 in this problem; repeat>1 is shape-inconsistent in the
  // reference for C != 1, so it is structurally always 1).
  float* out = (float*)d_out;
  float* W2T = (float*)d_ws;                     // (HH1+1) x HH2 floats

  // zero the dummy padding row (row HH1) of W2T
  hipMemsetAsync(W2T + (size_t)HH1 * HH2, 0, HH2 * sizeof(float), stream);

  dim3 tg(HH1 / 32, HH2 / 32);
  transpose_w2<<<tg, 256, 0, stream>>>(W2, W2T);

  snn_main<<<BB, 256, 0, stream>>>(x, W1, b1, W2T, b2, W3, b3, out);
}

// Round 2
// 698.176 us; speedup vs baseline: 1.5594x; 1.5594x over previous
//
#include <hip/hip_runtime.h>

#define BB  1024
#define TT  128
#define HH1 512
#define HH2 256
#define CC  18
#define ROWB   1024               // bytes per W2T row (HH2*4)
#define DUMMY1 (HH1 * ROWB)       // byte offset of the zeroed pad row of W2T
#define W3STR  (CC * 4)           // 72 bytes per w3t row
#define DUMMY2 (HH2 * W3STR)      // zeroed pad row of w3t

typedef float float4v __attribute__((ext_vector_type(4)));

// Transpose W2 (256 x 512) -> W2T (512 x 256).
__global__ __launch_bounds__(256) void transpose_w2(const float* __restrict__ in,
                                                    float* __restrict__ out)
{
  __shared__ float tile[32][33];
  int bx = blockIdx.x * 32;            // h1
  int by = blockIdx.y * 32;            // h2
  int tx = threadIdx.x & 31;
  int ty = threadIdx.x >> 5;
#pragma unroll
  for (int j = 0; j < 32; j += 8)
    tile[ty + j][tx] = in[(by + ty + j) * HH1 + bx + tx];
  __syncthreads();
#pragma unroll
  for (int j = 0; j < 32; j += 8)
    out[(bx + ty + j) * HH2 + by + tx] = tile[tx][ty + j];
}

// One block per batch row; 256 threads = 4 waves.
__global__ __launch_bounds__(256) void snn_main(const float* __restrict__ x,
    const float* __restrict__ W1, const float* __restrict__ b1,
    const float* __restrict__ W2T, const float* __restrict__ b2,
    const float* __restrict__ W3, const float* __restrict__ b3,
    float* __restrict__ out)
{
  __shared__ float xrow[TT];
  __shared__ float w3t[(HH2 + 1) * CC];            // [h2][c], +1 zero row
  __shared__ __align__(16) unsigned long long m1s[8];
  __shared__ __align__(16) unsigned long long m2s[4];
  __shared__ unsigned int list1[HH1 + 16];         // prescaled byte offsets
  __shared__ float partial[4 * HH2];
  __shared__ unsigned int list2[HH2 + 8];          // wave-0 private

  const int b    = blockIdx.x;
  const int tid  = threadIdx.x;
  const int wv   = tid >> 6;
  const int lane = tid & 63;
  const unsigned lane16 = (unsigned)lane * 16u;

  for (int i = tid; i < TT; i += 256) xrow[i] = x[b * TT + i];
  for (int i = tid; i < HH2 * CC; i += 256) {
    int c = i >> 8, h2 = i & 255;                  // W3 is [c][h2], 18x256
    w3t[h2 * CC + c] = W3[i];
  }
  if (tid < CC) w3t[HH2 * CC + tid] = 0.0f;        // zero pad row

  const float w1a = W1[tid],        w1b = W1[tid + 256];
  const float b1a = b1[tid],        b1b = b1[tid + 256];
  const float b2r = b2[tid];
  const int   j3  = (lane < 3 * CC) ? (lane / CC) : 0;  // 0..2
  const int   c3  = lane - ((lane < 3 * CC) ? j3 * CC : lane); // c for lanes<54
  const float b3r = (wv == 0 && lane < CC) ? b3[lane] : 0.0f;

  float v1a = 0.0f, v1b = 0.0f, v2 = 0.0f, v3 = 0.0f, acc = 0.0f;

  __syncthreads();

  for (int t = 0; t < TT; ++t) {
    float xt = xrow[t];

    // ---- layer 1 (bit-exact: mul-rn, add-rn, add-rn) ----
    float iA = __fadd_rn(__fmul_rn(xt, w1a), b1a);
    v1a = __fadd_rn(v1a, iA);
    bool sA = (v1a >= 1.0f);  v1a = sA ? (v1a - 1.0f) : v1a;
    float iB = __fadd_rn(__fmul_rn(xt, w1b), b1b);
    v1b = __fadd_rn(v1b, iB);
    bool sB = (v1b >= 1.0f);  v1b = sB ? (v1b - 1.0f) : v1b;
    unsigned long long mA = __ballot(sA);
    unsigned long long mB = __ballot(sB);
    if (lane == 0) { m1s[wv] = mA; m1s[4 + wv] = mB; }
    __syncthreads();                                       // A: m1 ready

    // ---- popcount + prefix (redundant, all threads) ----
    unsigned long long mw[8];
#pragma unroll
    for (int k = 0; k < 8; ++k) mw[k] = m1s[k];
    int base[8]; int cnt1 = 0;
#pragma unroll
    for (int k = 0; k < 8; ++k) { base[k] = cnt1; cnt1 += (int)__popcll(mw[k]); }

    // ---- parallel compaction: wave wv compacts words 2wv, 2wv+1 ----
#pragma unroll
    for (int q = 0; q < 2; ++q) {
      int k = 2 * wv + q;
      unsigned long long m = mw[k];
      if ((m >> lane) & 1ull) {
        int rank = __builtin_amdgcn_mbcnt_hi((unsigned)(m >> 32),
                   __builtin_amdgcn_mbcnt_lo((unsigned)m, 0u));
        list1[base[k] + rank] = (unsigned)((k * 64 + lane) * ROWB);
      }
    }
    int rcnt1 = (cnt1 + 15) & ~15;                  // pad to x16 (K mult of 4)
    if (tid < rcnt1 - cnt1) list1[cnt1 + tid] = (unsigned)DUMMY1;
    __syncthreads();                                       // B: list1 ready

    // ---- layer 2 gather: wave wv takes terms i = 4k+wv, float4 per lane ----
    float4v s4 = {0.0f, 0.0f, 0.0f, 0.0f};
    const int K = rcnt1 >> 2;                       // terms per wave (mult of 4)
    for (int k = 0; k < K; k += 4) {
      unsigned o0 = list1[((k + 0) << 2) + wv];
      unsigned o1 = list1[((k + 1) << 2) + wv];
      unsigned o2 = list1[((k + 2) << 2) + wv];
      unsigned o3 = list1[((k + 3) << 2) + wv];
      float4v f0 = *(const float4v*)((const char*)W2T + (o0 + lane16));
      float4v f1 = *(const float4v*)((const char*)W2T + (o1 + lane16));
      float4v f2 = *(const float4v*)((const char*)W2T + (o2 + lane16));
      float4v f3 = *(const float4v*)((const char*)W2T + (o3 + lane16));
      s4 += f0; s4 += f1; s4 += f2; s4 += f3;
    }
    *(float4v*)&partial[wv * HH2 + lane * 4] = s4;
    __syncthreads();                                       // C: partials ready

    float d2 = __fadd_rn(__fadd_rn(__fadd_rn(partial[tid], partial[HH2 + tid]),
                                   partial[2 * HH2 + tid]), partial[3 * HH2 + tid]);
    float i2 = __fadd_rn(d2, b2r);
    v2 = __fadd_rn(v2, i2);
    bool s2 = (v2 >= 1.0f);  v2 = s2 ? (v2 - 1.0f) : v2;
    unsigned long long mW = __ballot(s2);
    if (lane == 0) m2s[wv] = mW;
    __syncthreads();                                       // D: m2 ready

    // ---- layer 3: wave 0 only ----
    if (wv == 0) {
      unsigned long long n[4];
#pragma unroll
      for (int k = 0; k < 4; ++k) n[k] = m2s[k];
      int bas2[4]; int cnt2 = 0;
#pragma unroll
      for (int k = 0; k < 4; ++k) { bas2[k] = cnt2; cnt2 += (int)__popcll(n[k]); }
#pragma unroll
      for (int k = 0; k < 4; ++k) {
        unsigned long long m = n[k];
        if ((m >> lane) & 1ull) {
          int rank = __builtin_amdgcn_mbcnt_hi((unsigned)(m >> 32),
                     __builtin_amdgcn_mbcnt_lo((unsigned)m, 0u));
          list2[bas2[k] + rank] = (unsigned)((k * 64 + lane) * W3STR);
        }
      }
      int rcnt2 = cnt2 + ((3 - (cnt2 % 3)) % 3);    // pad to x3
      if (lane < rcnt2 - cnt2) list2[cnt2 + lane] = (unsigned)DUMMY2;
      __builtin_amdgcn_wave_barrier();
      __builtin_amdgcn_s_waitcnt(0xc07f);           // lgkmcnt(0): wave-local LDS visibility
      __builtin_amdgcn_wave_barrier();

      float d3 = 0.0f;
      if (lane < 3 * CC) {                          // lane = j3*18 + c3
        for (int k = 0; k < rcnt2; k += 3) {
          unsigned o = list2[k + j3];
          d3 = __fadd_rn(d3, *(const float*)((const char*)w3t + o + c3 * 4));
        }
      }
      float dA = __shfl(d3, lane + 18);
      float dB = __shfl(d3, lane + 36);
      if (lane < CC) {
        float tot = __fadd_rn(__fadd_rn(d3, dA), dB);   // j=0 + j=1 + j=2
        float i3  = __fadd_rn(tot, b3r);
        v3 = __fadd_rn(v3, i3);
        bool s3 = (v3 >= 1.0f);  v3 = s3 ? (v3 - 1.0f) : v3;
        acc = __fadd_rn(acc, s3 ? 1.0f : 0.0f);
      }
    }
  }

  if (wv == 0 && lane < CC) out[b * CC + lane] = acc * (1.0f / TT);
}

extern "C" void kernel_launch(void* const* d_in, const int* in_sizes, int n_in,
                              void* d_out, int out_size, void* d_ws, size_t ws_size,
                              hipStream_t stream)
{
  (void)in_sizes; (void)n_in; (void)out_size; (void)ws_size;
  const float* x  = (const float*)d_in[0];
  const float* W1 = (const float*)d_in[1];
  const float* b1 = (const float*)d_in[2];
  const float* W2 = (const float*)d_in[3];
  const float* b2 = (const float*)d_in[4];
  const float* W3 = (const float*)d_in[5];
  const float* b3 = (const float*)d_in[6];
  // d_in[7] = repeat (structurally 1 for this problem shape)
  float* out = (float*)d_out;
  float* W2T = (float*)d_ws;                        // (HH1+1) x HH2 floats

  hipMemsetAsync(W2T + (size_t)HH1 * HH2, 0, HH2 * sizeof(float), stream);

  dim3 tg(HH1 / 32, HH2 / 32);
  transpose_w2<<<tg, 256, 0, stream>>>(W2, W2T);

  snn_main<<<BB, 256, 0, stream>>>(x, W1, b1, W2T, b2, W3, b3, out);
}